// Round 1
// baseline (1305.737 us; speedup 1.0000x reference)
//
#include <hip/hip_runtime.h>

// InnerProduct: ip[r,p] = sum_f w[p,f]^2 * sum_e x[r,f,e]^2
// x: [32768, 64, 128] fp32, w: [10, 64] fp32, out: [32768, 10] fp32
// Memory-bound streaming kernel: read x once (1.074 GB), floor ~170 us @ 6.3 TB/s.

#define BATCH   32768
#define NF      64
#define EMBED   128
#define OUT_N   10
#define ROW_F   (NF * EMBED)   // 8192 floats per row
#define W2_PAD  12             // pad 10 -> 12 floats (48B, 16B-aligned rows)

__global__ __launch_bounds__(256) void ip_kernel(
    const float* __restrict__ x,
    const float* __restrict__ w,
    float* __restrict__ out)
{
    // Stage squared+transposed weights in LDS: w2[f][p] = w[p][f]^2
    __shared__ float w2[NF * W2_PAD];
    for (int i = threadIdx.x; i < OUT_N * NF; i += 256) {
        int p = i >> 6;        // i / 64
        int f = i & 63;        // i % 64
        float v = w[i];
        w2[f * W2_PAD + p] = v * v;
    }
    __syncthreads();

    const int lane = threadIdx.x & 63;
    const int wid  = threadIdx.x >> 6;
    const int row  = blockIdx.x * 4 + wid;   // grid sized so row < BATCH exactly

    const float4* __restrict__ base =
        (const float4*)(x + (size_t)row * ROW_F);

    float acc[OUT_N];
    #pragma unroll
    for (int p = 0; p < OUT_N; ++p) acc[p] = 0.0f;

    const int half = lane >> 5;  // 0 for lanes 0..31, 1 for lanes 32..63

    // Each wave iteration: 64 lanes x float4 = 256 floats = exactly 2 fields.
    // field of this lane's float4 = 2*t + half (wave-half-uniform).
    #pragma unroll 8
    for (int t = 0; t < 32; ++t) {
        float4 v = base[t * 64 + lane];
        float s = v.x * v.x + v.y * v.y + v.z * v.z + v.w * v.w;

        const float4* wr4 = (const float4*)&w2[(2 * t + half) * W2_PAD];
        float4 w0 = wr4[0];          // w2[f][0..3]  (LDS broadcast)
        float4 w1 = wr4[1];          // w2[f][4..7]
        float4 w2v = wr4[2];         // w2[f][8..11] (10,11 are pad garbage)

        acc[0] += s * w0.x;  acc[1] += s * w0.y;
        acc[2] += s * w0.z;  acc[3] += s * w0.w;
        acc[4] += s * w1.x;  acc[5] += s * w1.y;
        acc[6] += s * w1.z;  acc[7] += s * w1.w;
        acc[8] += s * w2v.x; acc[9] += s * w2v.y;
    }

    // Butterfly reduction across the 64-lane wave (all lanes end with full sums)
    #pragma unroll
    for (int off = 32; off >= 1; off >>= 1) {
        #pragma unroll
        for (int p = 0; p < OUT_N; ++p)
            acc[p] += __shfl_xor(acc[p], off, 64);
    }

    if (lane == 0) {
        float* o = out + (size_t)row * OUT_N;
        #pragma unroll
        for (int p = 0; p < OUT_N; ++p) o[p] = acc[p];
    }
}

extern "C" void kernel_launch(void* const* d_in, const int* in_sizes, int n_in,
                              void* d_out, int out_size, void* d_ws, size_t ws_size,
                              hipStream_t stream) {
    const float* x = (const float*)d_in[0];   // [32768, 64, 128]
    const float* w = (const float*)d_in[1];   // [10, 64]
    float* out = (float*)d_out;               // [32768, 10]

    // one wave per row, 4 waves (256 threads) per block
    dim3 grid(BATCH / 4);
    dim3 block(256);
    ip_kernel<<<grid, block, 0, stream>>>(x, w, out);
}